// Round 3
// baseline (40.860 us; speedup 1.0000x reference)
//
#include <hip/hip_runtime.h>
#include <hip/hip_bf16.h>
#include <stdint.h>

// Mahalanobis: out[i] = delta_i @ S_inv @ delta_i^T, delta = x - x_fit
// N=65536, D=256.
// Round 2 -> 3: round 2's VGPR_Count=48 proved the compiler re-sank the
// "register-resident" S loads back into the MFMA loop (legal remat of const
// loads) -> still latency-bound. Now the B fragments are pinned via opaque
// asm ("+v") after load, making remat illegal. rt-loop becomes pure LDS+MFMA.

#define D 256
#define BLOCK_T 512           // 8 waves
#define ROWS_PER_BLOCK 64
#define LDS_STRIDE 264        // 256 + 8 bf16 pad: breaks stride-256 bank conflict

typedef __attribute__((ext_vector_type(4))) float f32x4;
typedef __attribute__((ext_vector_type(8))) short bf16x8;

static __device__ __forceinline__ unsigned short f2bf(float f) {
    union { float f; uint32_t u; } v; v.f = f;
    uint32_t u = v.u;
    return (unsigned short)((u + 0x7FFFu + ((u >> 16) & 1u)) >> 16);
}
static __device__ __forceinline__ float bf2f(unsigned short s) {
    union { uint32_t u; float f; } v; v.u = ((uint32_t)s) << 16;
    return v.f;
}

// S_inv fp32 -> bf16 (row-major; S is symmetric so this is also S^T)
__global__ void prep_S_kernel(const float* __restrict__ S, unsigned short* __restrict__ Sb) {
    int i = (blockIdx.x * 256 + threadIdx.x) * 4;
    f32x4 v = *(const f32x4*)(S + i);
    uint32_t lo = (uint32_t)f2bf(v[0]) | ((uint32_t)f2bf(v[1]) << 16);
    uint32_t hi = (uint32_t)f2bf(v[2]) | ((uint32_t)f2bf(v[3]) << 16);
    *(uint2*)(Sb + i) = make_uint2(lo, hi);
}

__global__ __launch_bounds__(BLOCK_T, 4) void mahal_kernel(
    const float* __restrict__ x, const float* __restrict__ xf,
    const unsigned short* __restrict__ Sb, float* __restrict__ out)
{
    __shared__ unsigned short ld[ROWS_PER_BLOCK * LDS_STRIDE]; // 33792 B
    __shared__ float psum[8 * ROWS_PER_BLOCK];                 // 2048 B

    const int t    = threadIdx.x;
    const int w    = t >> 6;      // wave 0..7: owns cols [w*32, w*32+32)
    const int lane = t & 63;
    const int lo4  = lane & 15;
    const int hi2  = lane >> 4;
    const int blockRow = blockIdx.x * ROWS_PER_BLOCK;

    // ---- B fragments: full 32-col slice of S. Issued FIRST (complete under
    // the staging phase), then pinned below so they stay register-resident.
    // B[k][n] = S[k][n] = S[n][k] (symmetric) -> row n contiguous along k
    bf16x8 b0[8], b1[8];
    {
        const unsigned short* Sp = Sb + (w * 32 + lo4) * D + hi2 * 8;
        #pragma unroll
        for (int kb = 0; kb < 8; ++kb) {
            b0[kb] = *(const bf16x8*)(Sp + kb * 32);
            b1[kb] = *(const bf16x8*)(Sp + 16 * D + kb * 32);
        }
    }

    // ---- stage delta (bf16) into LDS: each thread does 8 cols x 4 rows ----
    {
        const int lrow0 = t >> 5;          // 0..15
        const int col   = (t & 31) * 8;    // 0..248
        #pragma unroll
        for (int i = 0; i < 4; ++i) {
            const int lrow = i * 16 + lrow0;
            const int g = (blockRow + lrow) * D + col;
            f32x4 a0 = *(const f32x4*)(x  + g);
            f32x4 a1 = *(const f32x4*)(x  + g + 4);
            f32x4 c0 = *(const f32x4*)(xf + g);
            f32x4 c1 = *(const f32x4*)(xf + g + 4);
            bf16x8 o;
            o[0] = (short)f2bf(a0[0] - c0[0]);
            o[1] = (short)f2bf(a0[1] - c0[1]);
            o[2] = (short)f2bf(a0[2] - c0[2]);
            o[3] = (short)f2bf(a0[3] - c0[3]);
            o[4] = (short)f2bf(a1[0] - c1[0]);
            o[5] = (short)f2bf(a1[1] - c1[1]);
            o[6] = (short)f2bf(a1[2] - c1[2]);
            o[7] = (short)f2bf(a1[3] - c1[3]);
            *(bf16x8*)(&ld[lrow * LDS_STRIDE + col]) = o;
        }
    }

    // ---- pin B fragments: value now defined by opaque asm -> remat illegal
    #pragma unroll
    for (int kb = 0; kb < 8; ++kb) {
        asm volatile("" : "+v"(b0[kb]));
        asm volatile("" : "+v"(b1[kb]));
    }

    __syncthreads();

    // ---- 4 row-tiles of 16; each wave computes T over its 32 cols ----
    #pragma unroll
    for (int rt = 0; rt < 4; ++rt) {
        f32x4 acc0 = (f32x4){0.f, 0.f, 0.f, 0.f};
        f32x4 acc1 = (f32x4){0.f, 0.f, 0.f, 0.f};
        const unsigned short* A = &ld[(rt * 16 + lo4) * LDS_STRIDE + hi2 * 8];
        #pragma unroll
        for (int kb = 0; kb < 8; ++kb) {
            bf16x8 a = *(const bf16x8*)(A + kb * 32);
            acc0 = __builtin_amdgcn_mfma_f32_16x16x32_bf16(a, b0[kb], acc0, 0, 0, 0);
            acc1 = __builtin_amdgcn_mfma_f32_16x16x32_bf16(a, b1[kb], acc1, 0, 0, 0);
        }

        // epilogue: partial row-sums over this wave's 32 cols
        // C/D layout: col = lane&15, row = (lane>>4)*4 + reg
        const int c0 = w * 32 + lo4;
        const int c1 = w * 32 + 16 + lo4;
        float pr[4];
        #pragma unroll
        for (int r = 0; r < 4; ++r) {
            const int row = rt * 16 + hi2 * 4 + r;
            pr[r] = acc0[r] * bf2f(ld[row * LDS_STRIDE + c0])
                  + acc1[r] * bf2f(ld[row * LDS_STRIDE + c1]);
        }
        #pragma unroll
        for (int m = 1; m < 16; m <<= 1) {
            #pragma unroll
            for (int r = 0; r < 4; ++r) pr[r] += __shfl_xor(pr[r], m, 64);
        }
        if (lo4 == 0) {
            #pragma unroll
            for (int r = 0; r < 4; ++r)
                psum[w * ROWS_PER_BLOCK + rt * 16 + hi2 * 4 + r] = pr[r];
        }
    }
    __syncthreads();

    // ---- combine the 8 column-slice partials per row ----
    if (t < ROWS_PER_BLOCK) {
        float s = 0.f;
        #pragma unroll
        for (int ww = 0; ww < 8; ++ww) s += psum[ww * ROWS_PER_BLOCK + t];
        out[blockRow + t] = s;
    }
}

extern "C" void kernel_launch(void* const* d_in, const int* in_sizes, int n_in,
                              void* d_out, int out_size, void* d_ws, size_t ws_size,
                              hipStream_t stream) {
    const float* x  = (const float*)d_in[0];
    const float* xf = (const float*)d_in[1];
    const float* S  = (const float*)d_in[2];
    float* out = (float*)d_out;
    unsigned short* Sb = (unsigned short*)d_ws;  // 65536 * 2B = 128 KB scratch

    prep_S_kernel<<<(D * D) / (256 * 4), 256, 0, stream>>>(S, Sb);

    const int nRows = in_sizes[0] / D;           // 65536
    mahal_kernel<<<nRows / ROWS_PER_BLOCK, BLOCK_T, 0, stream>>>(x, xf, Sb, out);
}

// Round 4
// 38.468 us; speedup vs baseline: 1.0622x; 1.0622x over previous
//
#include <hip/hip_runtime.h>
#include <hip/hip_bf16.h>
#include <stdint.h>

// Mahalanobis: out[i] = delta_i @ S_inv @ delta_i^T, delta = x - x_fit
// N=65536, D=256.
// Round 3 -> 4: the "+v" pin failed (VGPR stayed 48 - the load+pin pair was
// sunk together into the MFMA loop). Now the B loads themselves are inline-asm
// global_load_dwordx4: a volatile asm load cannot be rematerialized or sunk,
// so the 16 fragments (64 VGPR) are genuinely register-resident. Explicit
// s_waitcnt vmcnt(0) + sched_barrier(0) before first MFMA use (rule #18).
// Also: LDS stride 264 -> 272 elems (2-chunk row rotation) to spread the
// A-fragment ds_read_b128 across all 32 banks.

#define D 256
#define BLOCK_T 512           // 8 waves
#define ROWS_PER_BLOCK 64
#define LDS_STRIDE 272        // 256 + 16 pad: chunk index == 2*row + kgrp mod 32

typedef __attribute__((ext_vector_type(4))) float f32x4;
typedef __attribute__((ext_vector_type(8))) short bf16x8;

static __device__ __forceinline__ unsigned short f2bf(float f) {
    union { float f; uint32_t u; } v; v.f = f;
    uint32_t u = v.u;
    return (unsigned short)((u + 0x7FFFu + ((u >> 16) & 1u)) >> 16);
}
static __device__ __forceinline__ float bf2f(unsigned short s) {
    union { uint32_t u; float f; } v; v.u = ((uint32_t)s) << 16;
    return v.f;
}

// Opaque 16B global load: cannot be sunk/rematerialized by the compiler.
static __device__ __forceinline__ bf16x8 gload16(const unsigned short* p) {
    bf16x8 r;
    asm volatile("global_load_dwordx4 %0, %1, off"
                 : "=v"(r) : "v"(p) : "memory");
    return r;
}

// S_inv fp32 -> bf16 (row-major; S is symmetric so this is also S^T)
__global__ void prep_S_kernel(const float* __restrict__ S, unsigned short* __restrict__ Sb) {
    int i = (blockIdx.x * 256 + threadIdx.x) * 4;
    f32x4 v = *(const f32x4*)(S + i);
    uint32_t lo = (uint32_t)f2bf(v[0]) | ((uint32_t)f2bf(v[1]) << 16);
    uint32_t hi = (uint32_t)f2bf(v[2]) | ((uint32_t)f2bf(v[3]) << 16);
    *(uint2*)(Sb + i) = make_uint2(lo, hi);
}

__global__ __launch_bounds__(BLOCK_T, 4) void mahal_kernel(
    const float* __restrict__ x, const float* __restrict__ xf,
    const unsigned short* __restrict__ Sb, float* __restrict__ out)
{
    __shared__ unsigned short ld[ROWS_PER_BLOCK * LDS_STRIDE]; // 34816 B
    __shared__ float psum[8 * ROWS_PER_BLOCK];                 // 2048 B

    const int t    = threadIdx.x;
    const int w    = t >> 6;      // wave 0..7: owns cols [w*32, w*32+32)
    const int lane = t & 63;
    const int lo4  = lane & 15;
    const int hi2  = lane >> 4;
    const int blockRow = blockIdx.x * ROWS_PER_BLOCK;

    // ---- B fragments: full 32-col slice of S, loaded ONCE via opaque asm.
    // B[k][n] = S[k][n] = S[n][k] (symmetric) -> row n contiguous along k.
    // Issued first; latency hidden under the delta-staging phase.
    bf16x8 b0[8], b1[8];
    {
        const unsigned short* Sp = Sb + (w * 32 + lo4) * D + hi2 * 8;
        #pragma unroll
        for (int kb = 0; kb < 8; ++kb) {
            b0[kb] = gload16(Sp + kb * 32);
            b1[kb] = gload16(Sp + 16 * D + kb * 32);
        }
    }

    // ---- stage delta (bf16) into LDS: each thread does 8 cols x 4 rows ----
    {
        const int lrow0 = t >> 5;          // 0..15
        const int col   = (t & 31) * 8;    // 0..248
        #pragma unroll
        for (int i = 0; i < 4; ++i) {
            const int lrow = i * 16 + lrow0;
            const int g = (blockRow + lrow) * D + col;
            f32x4 a0 = *(const f32x4*)(x  + g);
            f32x4 a1 = *(const f32x4*)(x  + g + 4);
            f32x4 c0 = *(const f32x4*)(xf + g);
            f32x4 c1 = *(const f32x4*)(xf + g + 4);
            bf16x8 o;
            o[0] = (short)f2bf(a0[0] - c0[0]);
            o[1] = (short)f2bf(a0[1] - c0[1]);
            o[2] = (short)f2bf(a0[2] - c0[2]);
            o[3] = (short)f2bf(a0[3] - c0[3]);
            o[4] = (short)f2bf(a1[0] - c1[0]);
            o[5] = (short)f2bf(a1[1] - c1[1]);
            o[6] = (short)f2bf(a1[2] - c1[2]);
            o[7] = (short)f2bf(a1[3] - c1[3]);
            *(bf16x8*)(&ld[lrow * LDS_STRIDE + col]) = o;
        }
    }

    __syncthreads();
    // We own the wait for the hand-written B loads (rule #18: waitcnt then
    // fence the scheduler so MFMA can't be hoisted above it).
    asm volatile("s_waitcnt vmcnt(0)" ::: "memory");
    __builtin_amdgcn_sched_barrier(0);

    // ---- 4 row-tiles of 16; each wave computes T over its 32 cols ----
    #pragma unroll
    for (int rt = 0; rt < 4; ++rt) {
        f32x4 acc0 = (f32x4){0.f, 0.f, 0.f, 0.f};
        f32x4 acc1 = (f32x4){0.f, 0.f, 0.f, 0.f};
        const unsigned short* A = &ld[(rt * 16 + lo4) * LDS_STRIDE + hi2 * 8];
        #pragma unroll
        for (int kb = 0; kb < 8; ++kb) {
            bf16x8 a = *(const bf16x8*)(A + kb * 32);
            acc0 = __builtin_amdgcn_mfma_f32_16x16x32_bf16(a, b0[kb], acc0, 0, 0, 0);
            acc1 = __builtin_amdgcn_mfma_f32_16x16x32_bf16(a, b1[kb], acc1, 0, 0, 0);
        }

        // epilogue: partial row-sums over this wave's 32 cols
        // C/D layout: col = lane&15, row = (lane>>4)*4 + reg
        const int c0 = w * 32 + lo4;
        const int c1 = w * 32 + 16 + lo4;
        float pr[4];
        #pragma unroll
        for (int r = 0; r < 4; ++r) {
            const int row = rt * 16 + hi2 * 4 + r;
            pr[r] = acc0[r] * bf2f(ld[row * LDS_STRIDE + c0])
                  + acc1[r] * bf2f(ld[row * LDS_STRIDE + c1]);
        }
        #pragma unroll
        for (int m = 1; m < 16; m <<= 1) {
            #pragma unroll
            for (int r = 0; r < 4; ++r) pr[r] += __shfl_xor(pr[r], m, 64);
        }
        if (lo4 == 0) {
            #pragma unroll
            for (int r = 0; r < 4; ++r)
                psum[w * ROWS_PER_BLOCK + rt * 16 + hi2 * 4 + r] = pr[r];
        }
    }
    __syncthreads();

    // ---- combine the 8 column-slice partials per row ----
    if (t < ROWS_PER_BLOCK) {
        float s = 0.f;
        #pragma unroll
        for (int ww = 0; ww < 8; ++ww) s += psum[ww * ROWS_PER_BLOCK + t];
        out[blockRow + t] = s;
    }
}

extern "C" void kernel_launch(void* const* d_in, const int* in_sizes, int n_in,
                              void* d_out, int out_size, void* d_ws, size_t ws_size,
                              hipStream_t stream) {
    const float* x  = (const float*)d_in[0];
    const float* xf = (const float*)d_in[1];
    const float* S  = (const float*)d_in[2];
    float* out = (float*)d_out;
    unsigned short* Sb = (unsigned short*)d_ws;  // 65536 * 2B = 128 KB scratch

    prep_S_kernel<<<(D * D) / (256 * 4), 256, 0, stream>>>(S, Sb);

    const int nRows = in_sizes[0] / D;           // 65536
    mahal_kernel<<<nRows / ROWS_PER_BLOCK, BLOCK_T, 0, stream>>>(x, xf, Sb, out);
}